// Round 8
// baseline (4082.742 us; speedup 1.0000x reference)
//
#include <hip/hip_runtime.h>
#include <stdint.h>

typedef unsigned short u16;
typedef uint32_t u32;
typedef __attribute__((ext_vector_type(8))) short short8;
typedef __attribute__((ext_vector_type(4))) float floatx4;

constexpr int BB = 128;     // batch
constexpr int TT = 64;      // time steps
constexpr int CC = 66;      // frame channels
constexpr int CPAD = 96;    // C padded to multiple of 32 (MFMA K-chunk)
constexpr int SS = 512;     // hidden
constexpr int NGATE = 1536; // 3*S
constexpr int NGRP = 8;     // groups; grp = blk&7 -> one XCD if round-robin
constexpr int GBLK = 16;    // blocks per group (s-split by 32)
constexpr int GS = 16 * SS; // per-group state slab elements (16 x 512)

template <bool B> struct BoolC { static constexpr bool value = B; };

__device__ __forceinline__ u16 f2bf(float f) {
    u32 u = __float_as_uint(f);
    u32 r = (u + 0x7fffu + ((u >> 16) & 1u)) >> 16;
    return (u16)r;
}
__device__ __forceinline__ float bf2f(u16 h) {
    return __uint_as_float(((u32)h) << 16);
}
__device__ __forceinline__ float sigm(float x) { return 1.f / (1.f + __expf(-x)); }
__device__ __forceinline__ float tanh_f(float x) { return 1.f - 2.f / (1.f + __expf(2.f * x)); }

// ---- DATA primitives.  F=true: sc0 only (bypass L1, served by the XCD's
// shared L2 -- valid only when producer+consumer share an XCD; runtime-
// checked).  F=false: sc0 sc1 system path (proven rounds 3-6). ----
template <bool F> __device__ __forceinline__ void st128(u16* p, short8 v) {
    if (F) asm volatile("global_store_dwordx4 %0, %1, off sc0"
                        :: "v"(p), "v"(v) : "memory");
    else   asm volatile("global_store_dwordx4 %0, %1, off sc0 sc1"
                        :: "v"(p), "v"(v) : "memory");
}
template <bool F> __device__ __forceinline__ void ld128(const u16* p, short8& d) {
    if (F) asm volatile("global_load_dwordx4 %0, %1, off sc0"
                        : "=v"(d) : "v"(p));
    else   asm volatile("global_load_dwordx4 %0, %1, off sc0 sc1"
                        : "=v"(d) : "v"(p));
}
__device__ __forceinline__ void vm_drain() {
    asm volatile("s_waitcnt vmcnt(0)" ::: "memory");
}
__device__ __forceinline__ void lds_drain() {
    asm volatile("s_waitcnt lgkmcnt(0)" ::: "memory");
}

// ---- FLAGS: always agent-scope relaxed atomics (device-coherent, proven
// rounds 3-6 -- cannot hang regardless of XCD mapping). ----
__device__ __forceinline__ void set_flag(int* f, int v) {
    if ((threadIdx.x & 63) == 0)
        __hip_atomic_store(f, v, __ATOMIC_RELAXED, __HIP_MEMORY_SCOPE_AGENT);
}
// Combined wait: lanes 0..31 poll the 32 f0 flags, lanes 32..63 poll f1.
__device__ __forceinline__ void wait2(const int* __restrict__ f0, int t0,
                                      const int* __restrict__ f1, int t1) {
    const int lane = threadIdx.x & 63;
    const int* p = (lane < 32) ? (f0 + lane * 16) : (f1 + (lane - 32) * 16);
    const int tgt = (lane < 32) ? t0 : t1;
    for (;;) {
        int v = __hip_atomic_load(p, __ATOMIC_RELAXED, __HIP_MEMORY_SCOPE_AGENT);
        if (__all(v >= tgt)) break;
        __builtin_amdgcn_s_sleep(1);
    }
    asm volatile("" ::: "memory");
}

// ---------------------------------------------------------------------------
// prep1: bf16 conversion of x (padded to 96), the 4 GRU weight matrices,
// and Ws -> bf16 [80][512] (c-padded) for the MFMA frames epilogue.
// ---------------------------------------------------------------------------
__global__ void prep1_kernel(const float* __restrict__ x,
                             const float* __restrict__ Wih0,
                             const float* __restrict__ Whh0,
                             const float* __restrict__ Wih1,
                             const float* __restrict__ Whh1,
                             const float* __restrict__ Ws,
                             u16* __restrict__ xbf, u16* __restrict__ wi0,
                             u16* __restrict__ wh0, u16* __restrict__ wi1,
                             u16* __restrict__ wh1, u16* __restrict__ wsb)
{
    const int N_xbf = BB * TT * CPAD;
    const int N_wi0 = NGATE * CPAD;
    const int N_whh = NGATE * SS;
    const int N_wsb = 80 * SS;
    const long total = (long)N_xbf + N_wi0 + 3L * N_whh + N_wsb;
    for (long i = (long)blockIdx.x * blockDim.x + threadIdx.x; i < total;
         i += (long)gridDim.x * blockDim.x) {
        long idx = i;
        if (idx < N_xbf) {
            int c = idx % CPAD; int bt = idx / CPAD;
            float v = (c < CC) ? x[(long)bt * CC + c] : 0.f;
            xbf[idx] = f2bf(v); continue;
        }
        idx -= N_xbf;
        if (idx < N_wi0) {
            int c = idx % CPAD; int n = idx / CPAD;
            float v = (c < CC) ? Wih0[(long)n * CC + c] : 0.f;
            wi0[idx] = f2bf(v); continue;
        }
        idx -= N_wi0;
        if (idx < N_whh) { wh0[idx] = f2bf(Whh0[idx]); continue; }
        idx -= N_whh;
        if (idx < N_whh) { wi1[idx] = f2bf(Wih1[idx]); continue; }
        idx -= N_whh;
        if (idx < N_whh) { wh1[idx] = f2bf(Whh1[idx]); continue; }
        idx -= N_whh;
        {
            int s = idx % SS; int c = idx / SS;
            wsb[idx] = (c < CC) ? f2bf(Ws[(long)c * SS + s]) : (u16)0;
        }
    }
}

// ---------------------------------------------------------------------------
// prep2: M = Wih0[:, :66] @ Ws (bf16); c0vec = Wih0 @ bs; gi0i = x_last@Wih0^T
// ---------------------------------------------------------------------------
__global__ void prep2_kernel(const float* __restrict__ x,
                             const float* __restrict__ Wih0,
                             const float* __restrict__ Ws,
                             const float* __restrict__ bs,
                             u16* __restrict__ Mbf, float* __restrict__ c0vec,
                             float* __restrict__ gi0i)
{
    const long NM = (long)NGATE * SS;
    const long NC = NGATE;
    const long NG = (long)BB * NGATE;
    const long total = NM + NC + NG;
    for (long i = (long)blockIdx.x * blockDim.x + threadIdx.x; i < total;
         i += (long)gridDim.x * blockDim.x) {
        long idx = i;
        if (idx < NM) {
            int s = idx % SS; int g = idx / SS;
            float acc = 0.f;
            for (int c = 0; c < CC; ++c)
                acc += Wih0[(long)g * CC + c] * Ws[(long)c * SS + s];
            Mbf[idx] = f2bf(acc); continue;
        }
        idx -= NM;
        if (idx < NC) {
            int g = idx;
            float acc = 0.f;
            for (int c = 0; c < CC; ++c) acc += Wih0[(long)g * CC + c] * bs[c];
            c0vec[g] = acc; continue;
        }
        idx -= NC;
        {
            int g = idx % NGATE; int b = idx / NGATE;
            float acc = 0.f;
            const float* xl = x + ((long)b * TT + (TT - 1)) * CC;
            for (int c = 0; c < CC; ++c) acc += xl[c] * Wih0[(long)g * CC + c];
            gi0i[idx] = acc;
        }
    }
}

// ---------------------------------------------------------------------------
// A-fragment direct load: 16 coherent dwordx4 per K=512 GEMM into registers.
// ---------------------------------------------------------------------------
template <bool F>
__device__ __forceinline__ void load_afrags(const u16* __restrict__ st,
                                            int l15, int quad, short8* a) {
#pragma unroll
    for (int kc = 0; kc < 16; ++kc)
        ld128<F>(st + (long)l15 * SS + kc * 32 + quad * 8, a[kc]);
}

#define MFMA_BF16(a, wp, acc) \
    acc = __builtin_amdgcn_mfma_f32_16x16x32_bf16(a, *(const short8*)(wp), acc, 0, 0, 0)

__device__ __forceinline__ void mm3_reg(const short8* a,
                                        const u16* __restrict__ w0,
                                        const u16* __restrict__ w1,
                                        const u16* __restrict__ w2,
                                        floatx4& A0, floatx4& A1, floatx4& A2) {
#pragma unroll
    for (int kc = 0; kc < 16; ++kc) {
        const int k = kc << 5;
        MFMA_BF16(a[kc], w0 + k, A0);
        MFMA_BF16(a[kc], w1 + k, A1);
        MFMA_BF16(a[kc], w2 + k, A2);
    }
}

template <int K>
__device__ __forceinline__ void mm3_g(const u16* __restrict__ aP,
                                      const u16* __restrict__ w0,
                                      const u16* __restrict__ w1,
                                      const u16* __restrict__ w2,
                                      floatx4& A0, floatx4& A1, floatx4& A2) {
#pragma unroll
    for (int k = 0; k < K; k += 32) {
        short8 a = *(const short8*)(aP + k);
        MFMA_BF16(a, w0 + k, A0);
        MFMA_BF16(a, w1 + k, A1);
        MFMA_BF16(a, w2 + k, A2);
    }
}

// ---------------------------------------------------------------------------
// Persistent kernel, wave-decoupled dataflow.  grp = blk&7, rank = blk>>3.
// Waves 0,1 = layer-0 (s-sub 0/1), waves 2,3 = layer-1.  Flags: agent atomics
// (always).  Data: sc0-only if the group is XCD-uniform (runtime check), else
// sc0sc1.  State stores coalesced via per-wave LDS 16x16 repack -> dwordx4.
// ---------------------------------------------------------------------------
__global__ __launch_bounds__(256, 1) void persist_kernel(
    const u16* __restrict__ xbf,
    const u16* __restrict__ wi0, const u16* __restrict__ wh0,
    const u16* __restrict__ wi1, const u16* __restrict__ wh1,
    const u16* __restrict__ Mbf,
    const float* __restrict__ bih0, const float* __restrict__ bhh0,
    const float* __restrict__ bih1, const float* __restrict__ bhh1,
    const float* __restrict__ c0vec, const float* __restrict__ gi0i,
    const float* __restrict__ Wt, const float* __restrict__ bt,
    u16* __restrict__ h0buf,   // [NGRP][4][16][512]
    u16* __restrict__ h1buf,   // [NGRP][2][16][512]
    u16* __restrict__ tstage,  // [NGRP][2][16][512]
    u16* __restrict__ temps,   // [64][128][512] (cached; read by frames)
    int* __restrict__ gflags,  // [NGRP][1024]: f0 at 0 (32x16), f1 at 512
    int* __restrict__ initfl)  // [NGRP*16*16]: xcd+1 per block, line-isolated
{
    __shared__ __align__(16) u16 tile[4][2][256];   // [wave][h/t][16x16]

    const int tid = threadIdx.x;
    const int wave = tid >> 6, lane = tid & 63;
    const int l15 = lane & 15, quad = lane >> 4;
    const int grp = blockIdx.x & 7, rank = blockIdx.x >> 3;
    const int b0g = grp * 16;
    const int wsub = wave & 1;
    const int sg0 = rank * 32 + wsub * 16;        // wave's 16-col s base
    const int sg = sg0 + l15;
    const bool l0w = wave < 2;

    u16* const h0g = h0buf + (long)grp * 4 * GS;
    u16* const h1g = h1buf + (long)grp * 2 * GS;
    u16* const tsg = tstage + (long)grp * 2 * GS;
    int* const f0 = gflags + grp * 1024;
    int* const f1 = f0 + 512;
    const int myflag = rank * 2 + wsub;

    // ---- runtime XCD-uniformity check (affects DATA path only; flags are
    // always device-coherent, so a wrong verdict cannot deadlock) ----
    // HW_REG_XCC_ID: id 20, offset 0, size 32 [measured: learn_hip m09]
    int xcd = __builtin_amdgcn_s_getreg((31 << 11) | 20) & 0xff;
    if (tid == 0)
        __hip_atomic_store(initfl + (grp * 16 + rank) * 16, xcd + 1,
                           __ATOMIC_RELAXED, __HIP_MEMORY_SCOPE_AGENT);
    __syncthreads();
    bool fast;
    {
        const int* p = initfl + (grp * 16 + (lane & 15)) * 16;
        int v;
        for (;;) {
            v = __hip_atomic_load(p, __ATOMIC_RELAXED,
                                  __HIP_MEMORY_SCOPE_AGENT);
            if (__all(v != 0)) break;
            __builtin_amdgcn_s_sleep(8);
        }
        int first = __shfl(v, 0);
        fast = __all(v == first);
    }

    // ---- per-thread constants & register state ----
    float bir, biz, bin, bhn;
    float c0r = 0.f, c0z = 0.f, c0n = 0.f;
    float hf[4] = {0.f, 0.f, 0.f, 0.f};
    float gi[12];
    float wt[32]; float btv = 0.f;
    u32 wreg[4][16];
#pragma unroll
    for (int r = 0; r < 4; ++r)
#pragma unroll
        for (int i = 0; i < 16; ++i) wreg[r][i] = 0u;

    if (l0w) {
        bir = bih0[sg] + bhh0[sg];
        biz = bih0[512 + sg] + bhh0[512 + sg];
        bin = bih0[1024 + sg];
        bhn = bhh0[1024 + sg];
        c0r = c0vec[sg]; c0z = c0vec[512 + sg]; c0n = c0vec[1024 + sg];
#pragma unroll
        for (int g3 = 0; g3 < 3; ++g3)
#pragma unroll
            for (int r = 0; r < 4; ++r)
                gi[g3 * 4 + r] =
                    gi0i[(long)(b0g + quad * 4 + r) * NGATE + g3 * 512 + sg];
    } else {
        bir = bih1[sg] + bhh1[sg];
        biz = bih1[512 + sg] + bhh1[512 + sg];
        bin = bih1[1024 + sg];
        bhn = bhh1[1024 + sg];
#pragma unroll
        for (int j = 0; j < 32; ++j) wt[j] = Wt[j];
        btv = bt[0];
    }

    const u16 *wiR, *wiZ, *wiN, *whR, *whZ, *whN, *mR, *mZ, *mN;
    if (l0w) {
        wiR = wi0 + (long)sg * CPAD + quad * 8;
        wiZ = wi0 + (long)(512 + sg) * CPAD + quad * 8;
        wiN = wi0 + (long)(1024 + sg) * CPAD + quad * 8;
        whR = wh0 + (long)sg * SS + quad * 8;
        whZ = wh0 + (long)(512 + sg) * SS + quad * 8;
        whN = wh0 + (long)(1024 + sg) * SS + quad * 8;
        mR = Mbf + (long)sg * SS + quad * 8;
        mZ = Mbf + (long)(512 + sg) * SS + quad * 8;
        mN = Mbf + (long)(1024 + sg) * SS + quad * 8;
    } else {
        wiR = wi1 + (long)sg * SS + quad * 8;
        wiZ = wi1 + (long)(512 + sg) * SS + quad * 8;
        wiN = wi1 + (long)(1024 + sg) * SS + quad * 8;
        whR = wh1 + (long)sg * SS + quad * 8;
        whZ = wh1 + (long)(512 + sg) * SS + quad * 8;
        whN = wh1 + (long)(1024 + sg) * SS + quad * 8;
        mR = mZ = mN = nullptr;
    }

    // coalesced-store lane roles (lanes 0..31): row, half
    const int srow = lane >> 1, shalf = lane & 1;
    u16* const myTileH = &tile[wave][0][0];
    u16* const myTileT = &tile[wave][1][0];

    auto run = [&](auto fc) {
        constexpr bool F = decltype(fc)::value;
        short8 fa[16], fb[16];
        if (l0w) {
            // ========== layer-0 wave: encoder t=0..62 ==========
#pragma clang loop unroll(disable)
            for (int t = 0; t < 63; ++t) {
                floatx4 aR = {0,0,0,0}, aZ = aR, aNI = aR, aNH = aR;
                const u16* aP =
                    xbf + ((long)(b0g + l15) * TT + t) * CPAD + quad * 8;
                mm3_g<CPAD>(aP, wiR, wiZ, wiN, aR, aZ, aNI);
                wait2(f0, t, f1, t - 3);   // data ready + depth-4 guard
                load_afrags<F>(h0g + (long)(t & 3) * GS, l15, quad, fa);
                vm_drain();
                mm3_reg(fa, whR, whZ, whN, aR, aZ, aNH);
#pragma unroll
                for (int r = 0; r < 4; ++r) {
                    float rr = sigm(aR[r] + bir);
                    float zz = sigm(aZ[r] + biz);
                    float nn = tanh_f(aNI[r] + bin + rr * (aNH[r] + bhn));
                    float hv = (1.f - zz) * nn + zz * hf[r];
                    hf[r] = hv;
                    myTileH[(quad * 4 + r) * 16 + l15] = f2bf(hv);
                }
                lds_drain();
                if (lane < 32) {
                    short8 v = *(const short8*)(myTileH + srow * 16 + shalf * 8);
                    st128<F>(h0g + (long)((t + 1) & 3) * GS +
                             (long)srow * SS + sg0 + shalf * 8, v);
                }
                vm_drain();
                set_flag(f0 + myflag * 16, t + 1);
            }
            // ========== layer-0 wave: decoder d=0..63 ==========
#pragma clang loop unroll(disable)
            for (int d = 0; d < 64; ++d) {
                const int t = 63 + d;
                wait2(f0, t, f1, (d > 0) ? t : 60);
                load_afrags<F>(h0g + (long)(t & 3) * GS, l15, quad, fa);
                if (d > 0)
                    load_afrags<F>(tsg + (long)((d - 1) & 1) * GS, l15, quad, fb);
                vm_drain();
                if (d > 0) {   // gi(d) = gi(d-1) + M @ temp(d-1) + c0
                    floatx4 tR = {0,0,0,0}, tZ = tR, tN = tR;
                    mm3_reg(fb, mR, mZ, mN, tR, tZ, tN);
#pragma unroll
                    for (int r = 0; r < 4; ++r) {
                        gi[r] += tR[r] + c0r;
                        gi[4 + r] += tZ[r] + c0z;
                        gi[8 + r] += tN[r] + c0n;
                    }
                }
                floatx4 hR = {0,0,0,0}, hZ = hR, hN4 = hR;
                mm3_reg(fa, whR, whZ, whN, hR, hZ, hN4);
#pragma unroll
                for (int r = 0; r < 4; ++r) {
                    float rr = sigm(gi[r] + hR[r] + bir);
                    float zz = sigm(gi[4 + r] + hZ[r] + biz);
                    float nn = tanh_f(gi[8 + r] + bin + rr * (hN4[r] + bhn));
                    float hv = (1.f - zz) * nn + zz * hf[r];
                    hf[r] = hv;
                    myTileH[(quad * 4 + r) * 16 + l15] = f2bf(hv);
                }
                lds_drain();
                if (lane < 32) {
                    short8 v = *(const short8*)(myTileH + srow * 16 + shalf * 8);
                    st128<F>(h0g + (long)((t + 1) & 3) * GS +
                             (long)srow * SS + sg0 + shalf * 8, v);
                }
                vm_drain();
                set_flag(f0 + myflag * 16, t + 1);
            }
        } else {
            // ========== layer-1 wave: u = 0..126 ==========
#pragma clang loop unroll(disable)
            for (int u = 0; u < 127; ++u) {
                const bool dec = (u >= 63);
                const int d = u - 63;
                wait2(f0, u + 1, f1, u);
                load_afrags<F>(h0g + (long)((u + 1) & 3) * GS, l15, quad, fa);
                load_afrags<F>(h1g + (long)(u & 1) * GS, l15, quad, fb);
                vm_drain();
                floatx4 aR = {0,0,0,0}, aZ = aR, aNI = aR, aNH = aR;
                mm3_reg(fa, wiR, wiZ, wiN, aR, aZ, aNI);
                mm3_reg(fb, whR, whZ, whN, aR, aZ, aNH);
#pragma unroll
                for (int r = 0; r < 4; ++r) {
                    float rr = sigm(aR[r] + bir);
                    float zz = sigm(aZ[r] + biz);
                    float nn = tanh_f(aNI[r] + bin + rr * (aNH[r] + bhn));
                    float hv = (1.f - zz) * nn + zz * hf[r];
                    hf[r] = hv;
                    u16 hb = f2bf(hv);
                    myTileH[(quad * 4 + r) * 16 + l15] = hb;
#pragma unroll
                    for (int i = 0; i < 15; ++i)
                        wreg[r][i] = (wreg[r][i] >> 16) | (wreg[r][i + 1] << 16);
                    wreg[r][15] = (wreg[r][15] >> 16) | ((u32)hb << 16);
                    if (dec) {
                        float tacc = btv;
#pragma unroll
                        for (int i = 0; i < 16; ++i) {
                            u32 wv = wreg[r][i];
                            tacc += __uint_as_float(wv << 16) * wt[2 * i];
                            tacc += __uint_as_float(wv & 0xffff0000u) * wt[2 * i + 1];
                        }
                        myTileT[(quad * 4 + r) * 16 + l15] = f2bf(tacc);
                    }
                }
                lds_drain();
                if (lane < 32) {
                    short8 v = *(const short8*)(myTileH + srow * 16 + shalf * 8);
                    st128<F>(h1g + (long)((u + 1) & 1) * GS +
                             (long)srow * SS + sg0 + shalf * 8, v);
                    if (dec) {
                        short8 w = *(const short8*)(myTileT + srow * 16 + shalf * 8);
                        st128<F>(tsg + (long)(d & 1) * GS +
                                 (long)srow * SS + sg0 + shalf * 8, w);
                        *(short8*)(temps + (long)d * (BB * SS) +
                                   (long)(b0g + srow) * SS + sg0 + shalf * 8) = w;
                    }
                }
                vm_drain();
                set_flag(f1 + myflag * 16, u + 1);
            }
        }
    };
    if (fast) run(BoolC<true>{});
    else      run(BoolC<false>{});
}

// ---------------------------------------------------------------------------
// frames epilogue (parallel, MFMA): per batch b,
//   P[e][c] = temp(e)[b] . Ws[c];  frames[b][e][c] = x_last + cumsum(P + bs)
// ---------------------------------------------------------------------------
__global__ __launch_bounds__(256) void frames_kernel(
    const u16* __restrict__ temps, const float* __restrict__ x,
    const u16* __restrict__ wsb, const float* __restrict__ bs,
    float* __restrict__ outp)
{
    const int b = blockIdx.x, tid = threadIdx.x;
    const int wave = tid >> 6, lane = tid & 63;
    const int l15 = lane & 15, quad = lane >> 4;
    __shared__ float P[64][81];

    const int e0 = wave * 16;
    floatx4 acc[5];
#pragma unroll
    for (int ct = 0; ct < 5; ++ct) acc[ct] = (floatx4){0.f, 0.f, 0.f, 0.f};
    const u16* aBase =
        temps + (long)(e0 + l15) * (BB * SS) + (long)b * SS + quad * 8;
#pragma unroll
    for (int kc = 0; kc < 16; ++kc) {
        short8 a = *(const short8*)(aBase + kc * 32);
#pragma unroll
        for (int ct = 0; ct < 5; ++ct) {
            const u16* wp = wsb + (long)(ct * 16 + l15) * SS + quad * 8 + kc * 32;
            MFMA_BF16(a, wp, acc[ct]);
        }
    }
#pragma unroll
    for (int ct = 0; ct < 5; ++ct)
#pragma unroll
        for (int r = 0; r < 4; ++r)
            P[e0 + quad * 4 + r][ct * 16 + l15] = acc[ct][r];
    __syncthreads();

    const int c = tid;
    if (c < CC) {
        float cum = x[((long)b * TT + (TT - 1)) * CC + c];
        const float bsv = bs[c];
        for (int e = 0; e < TT; ++e) {
            cum += P[e][c] + bsv;
            outp[(long)b * TT * CC + (long)e * CC + c] = cum;
        }
    }
}

// ---------------------------------------------------------------------------
extern "C" void kernel_launch(void* const* d_in, const int* in_sizes, int n_in,
                              void* d_out, int out_size, void* d_ws, size_t ws_size,
                              hipStream_t stream)
{
    const float* x    = (const float*)d_in[0];
    const float* Wih0 = (const float*)d_in[1];
    const float* Whh0 = (const float*)d_in[2];
    const float* bih0 = (const float*)d_in[3];
    const float* bhh0 = (const float*)d_in[4];
    const float* Wih1 = (const float*)d_in[5];
    const float* Whh1 = (const float*)d_in[6];
    const float* bih1 = (const float*)d_in[7];
    const float* bhh1 = (const float*)d_in[8];
    const float* Wt   = (const float*)d_in[9];
    const float* bt   = (const float*)d_in[10];
    const float* Ws   = (const float*)d_in[11];
    const float* bs   = (const float*)d_in[12];
    float* outp = (float*)d_out;

    char* p = (char*)d_ws;
    auto alloc = [&](size_t bytes) -> char* {
        char* r = p; p += (bytes + 255) & ~(size_t)255; return r;
    };
    u16* h0buf = (u16*)alloc((size_t)NGRP * 4 * GS * 2);
    u16* h1buf = (u16*)alloc((size_t)NGRP * 2 * GS * 2);
    u16* tstage = (u16*)alloc((size_t)NGRP * 2 * GS * 2);
    u16* xbf = (u16*)alloc((size_t)BB * TT * CPAD * 2);
    u16* wi0 = (u16*)alloc((size_t)NGATE * CPAD * 2);
    u16* wh0 = (u16*)alloc((size_t)NGATE * SS * 2);
    u16* wi1 = (u16*)alloc((size_t)NGATE * SS * 2);
    u16* wh1 = (u16*)alloc((size_t)NGATE * SS * 2);
    u16* Mbf = (u16*)alloc((size_t)NGATE * SS * 2);
    u16* wsb = (u16*)alloc((size_t)80 * SS * 2);
    float* c0vec = (float*)alloc((size_t)NGATE * 4);
    float* gi0i  = (float*)alloc((size_t)BB * NGATE * 4);
    u16* temps = (u16*)alloc((size_t)TT * BB * SS * 2);
    int* gflags = (int*)alloc((size_t)NGRP * 1024 * 4);
    int* initfl = (int*)alloc((size_t)NGRP * 16 * 16 * 4);

    hipMemsetAsync(h0buf, 0, (size_t)NGRP * 4 * GS * 2, stream);
    hipMemsetAsync(h1buf, 0, (size_t)NGRP * 2 * GS * 2, stream);
    hipMemsetAsync(gflags, 0, (size_t)NGRP * 1024 * 4, stream);
    hipMemsetAsync(initfl, 0, (size_t)NGRP * 16 * 16 * 4, stream);

    prep1_kernel<<<1024, 256, 0, stream>>>(x, Wih0, Whh0, Wih1, Whh1, Ws,
                                           xbf, wi0, wh0, wi1, wh1, wsb);
    prep2_kernel<<<1024, 256, 0, stream>>>(x, Wih0, Ws, bs, Mbf, c0vec, gi0i);

    persist_kernel<<<NGRP * GBLK, 256, 0, stream>>>(
        xbf, wi0, wh0, wi1, wh1, Mbf, bih0, bhh0, bih1, bhh1,
        c0vec, gi0i, Wt, bt, h0buf, h1buf, tstage, temps, gflags, initfl);

    frames_kernel<<<BB, 256, 0, stream>>>(temps, x, wsb, bs, outp);
}